// Round 1
// baseline (293.194 us; speedup 1.0000x reference)
//
#include <hip/hip_runtime.h>

typedef unsigned short u16;
typedef unsigned int u32;
using bf16x8 = __attribute__((ext_vector_type(8))) short;
using f32x4  = __attribute__((ext_vector_type(4))) float;

__device__ __forceinline__ u16 f2bf(float f) {
  u32 u = __float_as_uint(f);
  return (u16)((u + 0x7FFFu + ((u >> 16) & 1u)) >> 16);
}
__device__ __forceinline__ float bf2f(u16 h) {
  return __uint_as_float(((u32)h) << 16);
}

// ---------------- conv 3x3, 3->64, SAME, ReLU; out fmap[y][x][c] bf16 --------
__global__ __launch_bounds__(256) void conv3x3_relu_k(
    const float* __restrict__ img, const float* __restrict__ w,
    const float* __restrict__ bias, u16* __restrict__ fmap) {
  int p = blockIdx.x * 256 + threadIdx.x;  // 0..262143
  int y = p >> 9, x = p & 511;
  float v[27];
#pragma unroll
  for (int ci = 0; ci < 3; ++ci)
#pragma unroll
    for (int ky = 0; ky < 3; ++ky)
#pragma unroll
      for (int kx = 0; kx < 3; ++kx) {
        int yy = y + ky - 1, xx = x + kx - 1;
        bool ok = (yy >= 0) && (yy < 512) && (xx >= 0) && (xx < 512);
        v[(ci * 3 + ky) * 3 + kx] = ok ? img[ci * 262144 + yy * 512 + xx] : 0.f;
      }
  float acc[64];
#pragma unroll
  for (int co = 0; co < 64; ++co) {
    float s = bias[co];
#pragma unroll
    for (int q = 0; q < 27; ++q) s = fmaf(w[co * 27 + q], v[q], s);
    acc[co] = fmaxf(s, 0.f);
  }
  uint4* dst = (uint4*)((u32*)fmap + (size_t)p * 32);
#pragma unroll
  for (int q = 0; q < 8; ++q) {
    uint4 d;
    d.x = (u32)f2bf(acc[8 * q + 0]) | ((u32)f2bf(acc[8 * q + 1]) << 16);
    d.y = (u32)f2bf(acc[8 * q + 2]) | ((u32)f2bf(acc[8 * q + 3]) << 16);
    d.z = (u32)f2bf(acc[8 * q + 4]) | ((u32)f2bf(acc[8 * q + 5]) << 16);
    d.w = (u32)f2bf(acc[8 * q + 6]) | ((u32)f2bf(acc[8 * q + 7]) << 16);
    dst[q] = d;
  }
}

// ---------------- RoI max pool: block per roi; feat[n][c*49+py*7+px] bf16 ----
__global__ __launch_bounds__(256) void roipool_k(
    const u16* __restrict__ fmap, const int* __restrict__ regions,
    u16* __restrict__ feat) {
  int n = blockIdx.x, t = threadIdx.x;
  uint4* fdst = (uint4*)(feat + (size_t)n * 3136);  // 392 uint4 per row
  if (n >= 2000) {  // zero pad rows so GEMM needs no edge masking
    uint4 z; z.x = z.y = z.z = z.w = 0u;
    fdst[t % 392] = z;                       // covers 0..255 plus wrap
    int t2 = t + 256; if (t2 < 392) fdst[t2] = z;
    if (t < 392) fdst[t] = z;
    return;
  }
  int r0 = regions[2 * n], c0 = regions[2 * n + 1];
  __shared__ uint2 rows_u2[1792];  // 4 rows x 28 x x 64 c bf16 = 14336 B
  __shared__ uint4 frow4[392];     // 3136 bf16 = 6272 B
  u16* rows = (u16*)rows_u2;
  u16* frow = (u16*)frow4;
  for (int py = 0; py < 7; ++py) {
#pragma unroll
    for (int q = 0; q < 7; ++q) {
      int cid = t + q * 256;           // 0..1791, 8B chunks
      int i = cid / 448, rem = cid % 448;
      int xo = rem >> 4, c4 = (rem & 15) << 2;
      int yy = r0 + py * 4 + i, xx = c0 + xo;
      rows_u2[cid] = *(const uint2*)(fmap + (((size_t)(yy * 512 + xx)) << 6) + c4);
    }
    __syncthreads();
#pragma unroll
    for (int h = 0; h < 2; ++h) {
      int o = t + h * 256;
      if (o < 448) {
        int c = o & 63, px = o >> 6;
        float best = -3.0e38f;
#pragma unroll
        for (int i = 0; i < 4; ++i)
#pragma unroll
          for (int j = 0; j < 4; ++j)
            best = fmaxf(best, bf2f(rows[(i * 28 + px * 4 + j) * 64 + c]));
        frow[c * 49 + py * 7 + px] = f2bf(best);
      }
    }
    __syncthreads();
  }
  if (t < 392) fdst[t] = frow4[t];
  int t2 = t + 256;
  if (t2 < 392) fdst[t2] = frow4[t2];
}

// ---------------- fp32 -> bf16 conversion (vectorized) -----------------------
__global__ __launch_bounds__(256) void f2bf_k(const float* __restrict__ in,
                                              u16* __restrict__ out, int n4) {
  int idx = blockIdx.x * 256 + threadIdx.x;
  int stride = gridDim.x * 256;
  for (int i = idx; i < n4; i += stride) {
    float4 v = ((const float4*)in)[i];
    uint2 o;
    o.x = (u32)f2bf(v.x) | ((u32)f2bf(v.y) << 16);
    o.y = (u32)f2bf(v.z) | ((u32)f2bf(v.w) << 16);
    ((uint2*)out)[i] = o;
  }
}

// ---------------- bf16 GEMM (B^T layout): C[m][n] = relu(sum_k A[m][k]B[n][k] + b[n])
// BM=BN=128, BK=32, 256 threads = 4 waves (2x2 of 64x64), 16x16x32 MFMA.
__global__ __launch_bounds__(256) void gemm_bt_relu_k(
    const u16* __restrict__ A, const u16* __restrict__ B,
    const float* __restrict__ bias, u16* __restrict__ C, int N, int K) {
  __shared__ u16 As[128 * 32];  // 8 KB
  __shared__ u16 Bs[128 * 32];  // 8 KB
  int t = threadIdx.x;
  int lane = t & 63, wv = t >> 6;
  int wr = wv >> 1, wc = wv & 1;
  int n0 = blockIdx.x * 128, m0 = blockIdx.y * 128;
  int row = lane & 15, k0 = (lane >> 4) * 8;

  f32x4 acc[4][4] = {};
  const u16* Ab = A + (size_t)m0 * K;
  const u16* Bb = B + (size_t)n0 * K;

  for (int kk = 0; kk < K; kk += 32) {
#pragma unroll
    for (int q = 0; q < 2; ++q) {
      int cid = q * 256 + t;                 // 512 chunks of 16B per tile
      int r = cid >> 2, kc = (cid & 3) << 3; // row, k-chunk
      __builtin_amdgcn_global_load_lds(
          (const __attribute__((address_space(1))) void*)(Ab + (size_t)r * K + kk + kc),
          (__attribute__((address_space(3))) void*)((char*)As + cid * 16), 16, 0, 0);
      __builtin_amdgcn_global_load_lds(
          (const __attribute__((address_space(1))) void*)(Bb + (size_t)r * K + kk + kc),
          (__attribute__((address_space(3))) void*)((char*)Bs + cid * 16), 16, 0, 0);
    }
    __syncthreads();
    bf16x8 a[4], b[4];
#pragma unroll
    for (int i = 0; i < 4; ++i)
      a[i] = *(const bf16x8*)(As + (wr * 64 + i * 16 + row) * 32 + k0);
#pragma unroll
    for (int j = 0; j < 4; ++j)
      b[j] = *(const bf16x8*)(Bs + (wc * 64 + j * 16 + row) * 32 + k0);
#pragma unroll
    for (int i = 0; i < 4; ++i)
#pragma unroll
      for (int j = 0; j < 4; ++j)
        acc[i][j] = __builtin_amdgcn_mfma_f32_16x16x32_bf16(a[i], b[j], acc[i][j], 0, 0, 0);
    __syncthreads();
  }
#pragma unroll
  for (int i = 0; i < 4; ++i)
#pragma unroll
    for (int j = 0; j < 4; ++j)
#pragma unroll
      for (int r = 0; r < 4; ++r) {
        int rg = m0 + wr * 64 + i * 16 + (lane >> 4) * 4 + r;
        int cg = n0 + wc * 64 + j * 16 + (lane & 15);
        float v = acc[i][j][r] + bias[cg];
        v = fmaxf(v, 0.f);
        C[(size_t)rg * N + cg] = f2bf(v);
      }
}

// ---------------- cls/bbox heads: block per roi, 10 dots of K=4096 -----------
__global__ __launch_bounds__(256) void heads_k(
    const u16* __restrict__ h2, const float* __restrict__ cw,
    const float* __restrict__ cb, const float* __restrict__ bw,
    const float* __restrict__ bb, float* __restrict__ out) {
  int m = blockIdx.x, t = threadIdx.x;
  const u16* hrow = h2 + (size_t)m * 4096;
  float p[10];
#pragma unroll
  for (int j = 0; j < 10; ++j) p[j] = 0.f;
  for (int k = t; k < 4096; k += 256) {
    float v = bf2f(hrow[k]);
    p[0] = fmaf(v, cw[k], p[0]);
    p[1] = fmaf(v, cw[4096 + k], p[1]);
#pragma unroll
    for (int j = 0; j < 8; ++j) p[2 + j] = fmaf(v, bw[j * 4096 + k], p[2 + j]);
  }
#pragma unroll
  for (int j = 0; j < 10; ++j)
#pragma unroll
    for (int off = 32; off > 0; off >>= 1) p[j] += __shfl_down(p[j], off);
  __shared__ float red[4][10];
  int lane = t & 63, wv = t >> 6;
  if (lane == 0) {
#pragma unroll
    for (int j = 0; j < 10; ++j) red[wv][j] = p[j];
  }
  __syncthreads();
  if (t < 10) {
    float s = red[0][t] + red[1][t] + red[2][t] + red[3][t];
    s += (t < 2) ? cb[t] : bb[t - 2];
    if (t < 2) out[m * 2 + t] = s;
    else out[4000 + m * 8 + (t - 2)] = s;
  }
}

extern "C" void kernel_launch(void* const* d_in, const int* in_sizes, int n_in,
                              void* d_out, int out_size, void* d_ws, size_t ws_size,
                              hipStream_t stream) {
  const float* img    = (const float*)d_in[0];
  const int*   regions= (const int*)d_in[1];
  const float* conv_w = (const float*)d_in[2];
  const float* conv_b = (const float*)d_in[3];
  const float* fc1_w  = (const float*)d_in[4];
  const float* fc1_b  = (const float*)d_in[5];
  const float* fc2_w  = (const float*)d_in[6];
  const float* fc2_b  = (const float*)d_in[7];
  const float* cls_w  = (const float*)d_in[8];
  const float* cls_b  = (const float*)d_in[9];
  const float* bbox_w = (const float*)d_in[10];
  const float* bbox_b = (const float*)d_in[11];
  float* out = (float*)d_out;

  char* ws = (char*)d_ws;
  // layout (bytes):
  //   [0, 33554432)          fmap  [512][512][64] bf16   (later reused: h1, h2)
  //   [33554432, 46399488)   feat  [2048][3136] bf16
  //   [46399488, 72089600)   w1b   [4096][3136] bf16
  //   [72089600, 105644032)  w2b   [4096][4096] bf16
  u16* fmap = (u16*)(ws);
  u16* feat = (u16*)(ws + 33554432);
  u16* w1b  = (u16*)(ws + 46399488);
  u16* w2b  = (u16*)(ws + 72089600);
  u16* h1   = (u16*)(ws);              // aliases fmap (dead after pooling)
  u16* h2   = (u16*)(ws + 16777216);   // second half of fmap region

  conv3x3_relu_k<<<1024, 256, 0, stream>>>(img, conv_w, conv_b, fmap);
  roipool_k<<<2048, 256, 0, stream>>>(fmap, regions, feat);
  f2bf_k<<<2048, 256, 0, stream>>>(fc1_w, w1b, 4096 * 3136 / 4);
  f2bf_k<<<2048, 256, 0, stream>>>(fc2_w, w2b, 4096 * 4096 / 4);
  gemm_bt_relu_k<<<dim3(32, 16), 256, 0, stream>>>(feat, w1b, fc1_b, h1, 4096, 3136);
  gemm_bt_relu_k<<<dim3(32, 16), 256, 0, stream>>>(h1, w2b, fc2_b, h2, 4096, 4096);
  heads_k<<<2000, 256, 0, stream>>>(h2, cls_w, cls_b, bbox_w, bbox_b, out);
}

// Round 2
// 236.071 us; speedup vs baseline: 1.2420x; 1.2420x over previous
//
#include <hip/hip_runtime.h>

typedef unsigned short u16;
typedef unsigned int u32;
using bf16x8 = __attribute__((ext_vector_type(8))) short;
using f32x4  = __attribute__((ext_vector_type(4))) float;

__device__ __forceinline__ u16 f2bf(float f) {
  u32 u = __float_as_uint(f);
  return (u16)((u + 0x7FFFu + ((u >> 16) & 1u)) >> 16);
}
__device__ __forceinline__ float bf2f(u16 h) {
  return __uint_as_float(((u32)h) << 16);
}

// ---------------- conv 3x3, 3->64, SAME, ReLU; out fmap[y][x][c] bf16 --------
__global__ __launch_bounds__(256) void conv3x3_relu_k(
    const float* __restrict__ img, const float* __restrict__ w,
    const float* __restrict__ bias, u16* __restrict__ fmap) {
  int p = blockIdx.x * 256 + threadIdx.x;  // 0..262143
  int y = p >> 9, x = p & 511;
  float v[27];
#pragma unroll
  for (int ci = 0; ci < 3; ++ci)
#pragma unroll
    for (int ky = 0; ky < 3; ++ky)
#pragma unroll
      for (int kx = 0; kx < 3; ++kx) {
        int yy = y + ky - 1, xx = x + kx - 1;
        bool ok = (yy >= 0) && (yy < 512) && (xx >= 0) && (xx < 512);
        v[(ci * 3 + ky) * 3 + kx] = ok ? img[ci * 262144 + yy * 512 + xx] : 0.f;
      }
  float acc[64];
#pragma unroll
  for (int co = 0; co < 64; ++co) {
    float s = bias[co];
#pragma unroll
    for (int q = 0; q < 27; ++q) s = fmaf(w[co * 27 + q], v[q], s);
    acc[co] = fmaxf(s, 0.f);
  }
  uint4* dst = (uint4*)((u32*)fmap + (size_t)p * 32);
#pragma unroll
  for (int q = 0; q < 8; ++q) {
    uint4 d;
    d.x = (u32)f2bf(acc[8 * q + 0]) | ((u32)f2bf(acc[8 * q + 1]) << 16);
    d.y = (u32)f2bf(acc[8 * q + 2]) | ((u32)f2bf(acc[8 * q + 3]) << 16);
    d.z = (u32)f2bf(acc[8 * q + 4]) | ((u32)f2bf(acc[8 * q + 5]) << 16);
    d.w = (u32)f2bf(acc[8 * q + 6]) | ((u32)f2bf(acc[8 * q + 7]) << 16);
    dst[q] = d;
  }
}

// ---------------- RoI max pool: block per roi; feat[n][c*49+py*7+px] bf16 ----
__global__ __launch_bounds__(256) void roipool_k(
    const u16* __restrict__ fmap, const int* __restrict__ regions,
    u16* __restrict__ feat) {
  int n = blockIdx.x, t = threadIdx.x;
  uint4* fdst = (uint4*)(feat + (size_t)n * 3136);  // 392 uint4 per row
  if (n >= 2000) {  // zero pad rows so GEMM needs no edge masking
    uint4 z; z.x = z.y = z.z = z.w = 0u;
    fdst[t % 392] = z;
    int t2 = t + 256; if (t2 < 392) fdst[t2] = z;
    if (t < 392) fdst[t] = z;
    return;
  }
  int r0 = regions[2 * n], c0 = regions[2 * n + 1];
  __shared__ uint2 rows_u2[1792];  // 4 rows x 28 x 64c bf16 = 14336 B
  __shared__ uint4 frow4[392];     // 3136 bf16 = 6272 B
  u16* rows = (u16*)rows_u2;
  u16* frow = (u16*)frow4;
  for (int py = 0; py < 7; ++py) {
#pragma unroll
    for (int q = 0; q < 7; ++q) {
      int cid = t + q * 256;           // 0..1791, 8B chunks
      int i = cid / 448, rem = cid % 448;
      int xo = rem >> 4, c4 = (rem & 15) << 2;
      int yy = r0 + py * 4 + i, xx = c0 + xo;
      rows_u2[cid] = *(const uint2*)(fmap + (((size_t)(yy * 512 + xx)) << 6) + c4);
    }
    __syncthreads();
#pragma unroll
    for (int h = 0; h < 2; ++h) {
      int o = t + h * 256;
      if (o < 448) {
        int c = o & 63, px = o >> 6;
        float best = -3.0e38f;
#pragma unroll
        for (int i = 0; i < 4; ++i)
#pragma unroll
          for (int j = 0; j < 4; ++j)
            best = fmaxf(best, bf2f(rows[(i * 28 + px * 4 + j) * 64 + c]));
        frow[c * 49 + py * 7 + px] = f2bf(best);
      }
    }
    __syncthreads();
  }
  if (t < 392) fdst[t] = frow4[t];
  int t2 = t + 256;
  if (t2 < 392) fdst[t2] = frow4[t2];
}

// ---------------- fp32 -> bf16 conversion (vectorized) -----------------------
__global__ __launch_bounds__(256) void f2bf_k(const float* __restrict__ in,
                                              u16* __restrict__ out, int n4) {
  int idx = blockIdx.x * 256 + threadIdx.x;
  int stride = gridDim.x * 256;
  for (int i = idx; i < n4; i += stride) {
    float4 v = ((const float4*)in)[i];
    uint2 o;
    o.x = (u32)f2bf(v.x) | ((u32)f2bf(v.y) << 16);
    o.y = (u32)f2bf(v.z) | ((u32)f2bf(v.w) << 16);
    ((uint2*)out)[i] = o;
  }
}

// ---------------- 8-wave phase-pipelined bf16 GEMM (B^T):
// C[m][n] = relu(sum_k A[m][k]*B[n][k] + bias[n]), M=2048 fixed by grid.
// BM=128, BN=256, BK=64. 512 thr = 8 waves (2x4), per-wave 64x64 out.
// 3 LDS buffers (144 KB), prefetch distance 2, counted vmcnt(6).
// T2 XOR-swizzle: LDS[row][slot] holds global 16B-slot (slot ^ (row&7)).
__global__ __launch_bounds__(512, 2) void gemm8_bt_relu_k(
    const u16* __restrict__ A, const u16* __restrict__ B,
    const float* __restrict__ bias, u16* __restrict__ C, int N, int K) {
  __shared__ uint4 lds4[9216];  // 3 * (128*64 + 256*64) bf16 = 147456 B
  char* ldsb = (char*)lds4;
  const int t = threadIdx.x;
  const int lane = t & 63, wv = t >> 6;
  const int wm = wv >> 2, wn = wv & 3;

  int bid = blockIdx.x;                      // grid must be exactly 256
  int swz = ((bid & 7) << 5) | (bid >> 3);   // XCD-contiguous remap (bijective)
  const int nb = swz >> 4, mb = swz & 15;
  const int m0 = mb * 128, n0 = nb * 256;

  const u16* __restrict__ Ab = A + (size_t)m0 * K;
  const u16* __restrict__ Bb = B + (size_t)n0 * K;

  // staging: per-thread source with pre-applied inverse swizzle (rule #21)
  const int srow = t >> 3;                   // 0..63 row within a sweep
  const int sslot = (t & 7) ^ (srow & 7);    // permuted 16B slot in the row
  const u16* pA0 = Ab + (size_t)srow * K + sslot * 8;
  const u16* pA1 = pA0 + (size_t)64 * K;
  const u16* pB0 = Bb + (size_t)srow * K + sslot * 8;
  const u16* pB1 = pB0 + (size_t)64 * K;
  const u16* pB2 = pB0 + (size_t)128 * K;
  const u16* pB3 = pB0 + (size_t)192 * K;
  const int dof = t * 16;                    // linear LDS dest byte in sweep

#define G2L(src, ldst)                                                        \
  __builtin_amdgcn_global_load_lds(                                          \
      (const __attribute__((address_space(1))) void*)(src),                  \
      (__attribute__((address_space(3))) void*)(ldst), 16, 0, 0)

  // frag read addressing (swizzled)
  const int rA = wm * 64 + (lane & 15);
  const int rB = wn * 64 + (lane & 15);
  const int sl = lane >> 4;  // 0..3
#define LOFF(r, slot) (((r) << 7) + ((((slot) ^ ((r) & 7))) << 4))

  f32x4 acc[4][4] = {};
  bf16x8 bfr[4][2], afr[2][2];

  const int NT = K >> 6;
  // ---- prologue: stage tiles 0 and 1
  {
    char* A0 = ldsb; char* B0 = A0 + 16384;
    char* A1 = ldsb + 49152; char* B1 = A1 + 16384;
    G2L(pA0, A0 + dof); G2L(pA1, A0 + 8192 + dof);
    G2L(pB0, B0 + dof); G2L(pB1, B0 + 8192 + dof);
    G2L(pB2, B0 + 16384 + dof); G2L(pB3, B0 + 24576 + dof);
    G2L(pA0 + 64, A1 + dof); G2L(pA1 + 64, A1 + 8192 + dof);
    G2L(pB0 + 64, B1 + dof); G2L(pB1 + 64, B1 + 8192 + dof);
    G2L(pB2 + 64, B1 + 16384 + dof); G2L(pB3 + 64, B1 + 24576 + dof);
  }
  asm volatile("s_waitcnt vmcnt(6)" ::: "memory");  // tile 0 landed
  __builtin_amdgcn_s_barrier();

  int cb = 0;  // current buffer = tt % 3
  for (int tt = 0; tt < NT; ++tt) {
    const int pb = (cb + 2 >= 3) ? cb - 1 : cb + 2;  // (tt+2)%3
    const bool pf = (tt + 2) < NT;
    char* Acur = ldsb + cb * 49152; char* Bcur = Acur + 16384;
    char* Apf  = ldsb + pb * 49152; char* Bpf  = Apf + 16384;
    const int kof = (tt + 2) << 6;

    // ======== phase A: B-frags + A-frags(0,1); stage 3 sweeps; MFMA i=0,1
#pragma unroll
    for (int j = 0; j < 4; ++j) {
      bfr[j][0] = *(const bf16x8*)(Bcur + LOFF(rB + j * 16, sl));
      bfr[j][1] = *(const bf16x8*)(Bcur + LOFF(rB + j * 16, 4 + sl));
    }
#pragma unroll
    for (int i = 0; i < 2; ++i) {
      afr[i][0] = *(const bf16x8*)(Acur + LOFF(rA + i * 16, sl));
      afr[i][1] = *(const bf16x8*)(Acur + LOFF(rA + i * 16, 4 + sl));
    }
    if (pf) {
      G2L(pA0 + kof, Apf + dof);
      G2L(pA1 + kof, Apf + 8192 + dof);
      G2L(pB0 + kof, Bpf + dof);
    }
    __builtin_amdgcn_s_barrier();
    asm volatile("s_waitcnt lgkmcnt(0)" ::: "memory");
    __builtin_amdgcn_sched_barrier(0);
    __builtin_amdgcn_s_setprio(1);
#pragma unroll
    for (int i = 0; i < 2; ++i)
#pragma unroll
      for (int j = 0; j < 4; ++j) {
        acc[i][j] = __builtin_amdgcn_mfma_f32_16x16x32_bf16(afr[i][0], bfr[j][0], acc[i][j], 0, 0, 0);
        acc[i][j] = __builtin_amdgcn_mfma_f32_16x16x32_bf16(afr[i][1], bfr[j][1], acc[i][j], 0, 0, 0);
      }
    __builtin_amdgcn_s_setprio(0);
    __builtin_amdgcn_s_barrier();

    // ======== phase B: A-frags(2,3); stage 3 sweeps; MFMA i=2,3
#pragma unroll
    for (int i = 0; i < 2; ++i) {
      afr[i][0] = *(const bf16x8*)(Acur + LOFF(rA + (i + 2) * 16, sl));
      afr[i][1] = *(const bf16x8*)(Acur + LOFF(rA + (i + 2) * 16, 4 + sl));
    }
    if (pf) {
      G2L(pB1 + kof, Bpf + 8192 + dof);
      G2L(pB2 + kof, Bpf + 16384 + dof);
      G2L(pB3 + kof, Bpf + 24576 + dof);
    }
    __builtin_amdgcn_s_barrier();
    asm volatile("s_waitcnt lgkmcnt(0)" ::: "memory");
    __builtin_amdgcn_sched_barrier(0);
    __builtin_amdgcn_s_setprio(1);
#pragma unroll
    for (int i = 0; i < 2; ++i)
#pragma unroll
      for (int j = 0; j < 4; ++j) {
        acc[i + 2][j] = __builtin_amdgcn_mfma_f32_16x16x32_bf16(afr[i][0], bfr[j][0], acc[i + 2][j], 0, 0, 0);
        acc[i + 2][j] = __builtin_amdgcn_mfma_f32_16x16x32_bf16(afr[i][1], bfr[j][1], acc[i + 2][j], 0, 0, 0);
      }
    __builtin_amdgcn_s_setprio(0);
    // tile boundary: next tile's data must be resident before phase A reads it
    if (pf) {
      asm volatile("s_waitcnt vmcnt(6)" ::: "memory");   // keep t+2 in flight
    } else if (tt + 1 < NT) {
      asm volatile("s_waitcnt vmcnt(0)" ::: "memory");   // drain tail
    }
    __builtin_amdgcn_s_barrier();
    cb = (cb == 2) ? 0 : cb + 1;
  }
#undef G2L
#undef LOFF

  // ---- epilogue: bias + relu + bf16 store
  float bv[4];
#pragma unroll
  for (int j = 0; j < 4; ++j) bv[j] = bias[n0 + wn * 64 + j * 16 + (lane & 15)];
#pragma unroll
  for (int i = 0; i < 4; ++i)
#pragma unroll
    for (int j = 0; j < 4; ++j) {
      int cg = n0 + wn * 64 + j * 16 + (lane & 15);
#pragma unroll
      for (int r = 0; r < 4; ++r) {
        int rg = m0 + wm * 64 + i * 16 + (lane >> 4) * 4 + r;
        float v = fmaxf(acc[i][j][r] + bv[j], 0.f);
        C[(size_t)rg * N + cg] = f2bf(v);
      }
    }
}

// ---------------- cls/bbox heads: block per roi, 10 dots of K=4096 -----------
__global__ __launch_bounds__(256) void heads_k(
    const u16* __restrict__ h2, const float* __restrict__ cw,
    const float* __restrict__ cb, const float* __restrict__ bw,
    const float* __restrict__ bb, float* __restrict__ out) {
  int m = blockIdx.x, t = threadIdx.x;
  const u16* hrow = h2 + (size_t)m * 4096;
  float p[10];
#pragma unroll
  for (int j = 0; j < 10; ++j) p[j] = 0.f;
  for (int k = t; k < 4096; k += 256) {
    float v = bf2f(hrow[k]);
    p[0] = fmaf(v, cw[k], p[0]);
    p[1] = fmaf(v, cw[4096 + k], p[1]);
#pragma unroll
    for (int j = 0; j < 8; ++j) p[2 + j] = fmaf(v, bw[j * 4096 + k], p[2 + j]);
  }
#pragma unroll
  for (int j = 0; j < 10; ++j)
#pragma unroll
    for (int off = 32; off > 0; off >>= 1) p[j] += __shfl_down(p[j], off);
  __shared__ float red[4][10];
  int lane = t & 63, wv = t >> 6;
  if (lane == 0) {
#pragma unroll
    for (int j = 0; j < 10; ++j) red[wv][j] = p[j];
  }
  __syncthreads();
  if (t < 10) {
    float s = red[0][t] + red[1][t] + red[2][t] + red[3][t];
    s += (t < 2) ? cb[t] : bb[t - 2];
    if (t < 2) out[m * 2 + t] = s;
    else out[4000 + m * 8 + (t - 2)] = s;
  }
}

extern "C" void kernel_launch(void* const* d_in, const int* in_sizes, int n_in,
                              void* d_out, int out_size, void* d_ws, size_t ws_size,
                              hipStream_t stream) {
  const float* img    = (const float*)d_in[0];
  const int*   regions= (const int*)d_in[1];
  const float* conv_w = (const float*)d_in[2];
  const float* conv_b = (const float*)d_in[3];
  const float* fc1_w  = (const float*)d_in[4];
  const float* fc1_b  = (const float*)d_in[5];
  const float* fc2_w  = (const float*)d_in[6];
  const float* fc2_b  = (const float*)d_in[7];
  const float* cls_w  = (const float*)d_in[8];
  const float* cls_b  = (const float*)d_in[9];
  const float* bbox_w = (const float*)d_in[10];
  const float* bbox_b = (const float*)d_in[11];
  float* out = (float*)d_out;

  char* ws = (char*)d_ws;
  // layout (bytes):
  //   [0, 33554432)          fmap  [512][512][64] bf16   (later reused: h1, h2)
  //   [33554432, 46399488)   feat  [2048][3136] bf16
  //   [46399488, 72089600)   w1b   [4096][3136] bf16
  //   [72089600, 105644032)  w2b   [4096][4096] bf16
  u16* fmap = (u16*)(ws);
  u16* feat = (u16*)(ws + 33554432);
  u16* w1b  = (u16*)(ws + 46399488);
  u16* w2b  = (u16*)(ws + 72089600);
  u16* h1   = (u16*)(ws);              // aliases fmap (dead after pooling)
  u16* h2   = (u16*)(ws + 16777216);   // second half of fmap region

  conv3x3_relu_k<<<1024, 256, 0, stream>>>(img, conv_w, conv_b, fmap);
  roipool_k<<<2048, 256, 0, stream>>>(fmap, regions, feat);
  f2bf_k<<<2048, 256, 0, stream>>>(fc1_w, w1b, 4096 * 3136 / 4);
  f2bf_k<<<2048, 256, 0, stream>>>(fc2_w, w2b, 4096 * 4096 / 4);
  gemm8_bt_relu_k<<<256, 512, 0, stream>>>(feat, w1b, fc1_b, h1, 4096, 3136);
  gemm8_bt_relu_k<<<256, 512, 0, stream>>>(h1, w2b, fc2_b, h2, 4096, 4096);
  heads_k<<<2000, 256, 0, stream>>>(h2, cls_w, cls_b, bbox_w, bbox_b, out);
}